// Round 1
// baseline (6021.736 us; speedup 1.0000x reference)
//
#include <hip/hip_runtime.h>

typedef _Float16 f16;
typedef _Float16 f16x8 __attribute__((ext_vector_type(8)));
typedef _Float16 f16x4 __attribute__((ext_vector_type(4)));
typedef float f32x4 __attribute__((ext_vector_type(4)));

#define L2E 1.4426950408889634f
#define K2E 2.8853900817779268f

// ---- workspace layout (bytes). total 95,764,480 (~95.8 MB)
#define O_PQV   0UL            // f32 [16384][512]  (aliased by GIH2C later)
#define O_GIH2C 0UL            // f16 [16384][1024]
#define O_CTX   33554432UL     // f16 [16384][256]
#define O_ENCF  41943040UL     // f16 [16384][256]
#define O_GIH1  50331648UL     // f16 [16384][1024]
#define O_DECH  83886080UL     // f16 [512][8192] frag-order
#define O_WQV   92274688UL     // f16 [512][256]
#define O_W1    92536832UL     // f16 [1024][512]
#define O_W2    93585408UL     // f16 [1024][512]
#define O_WHH1  94633984UL     // f16 [1024][256]
#define O_WHH2  95158272UL     // f16 [1024][256]
#define O_BQV   95682560UL     // f32 [512]
#define O_B1    95684608UL     // f32 [1024]
#define O_B2    95688704UL     // f32 [1024]
#define O_V2    95692800UL     // f32 [256]  (= -2*V)
#define O_SUMV  95693824UL     // f32 [1]
#define O_CPUB  95694848UL     // f16 [2][8192] frag-order c publish
#define O_H2PUB 95727616UL     // f16 [2][8192]
#define O_FLAGS 95760384UL     // int flag1[512], flag2[512]
#define WS_NEED 95764480UL

__device__ __forceinline__ float fast_sigmoid(float x){
  float e = __builtin_amdgcn_exp2f(-L2E * x);
  return __builtin_amdgcn_rcpf(1.f + e);
}
__device__ __forceinline__ float fast_tanh(float x){
  float e = __builtin_amdgcn_exp2f(K2E * x);
  return 1.f - 2.f * __builtin_amdgcn_rcpf(1.f + e);
}

// ============ prep: weight conversions, biases, cpub[1]=backward_cell_state =========
__global__ __launch_bounds__(256) void prep_kernel(
    const float* __restrict__ attn_W, const float* __restrict__ attn_b, const float* __restrict__ attn_V,
    const float* __restrict__ l1_Wih, const float* __restrict__ l1_Whh,
    const float* __restrict__ l1_bih, const float* __restrict__ l1_bhh,
    const float* __restrict__ l2_Wih, const float* __restrict__ l2_Whh,
    const float* __restrict__ l2_bih, const float* __restrict__ l2_bhh,
    const float* __restrict__ bcs, char* __restrict__ ws)
{
  long gid = (long)blockIdx.x*256 + threadIdx.x;
  if (gid < 131072){
    int j = (int)(gid >> 8), k = (int)(gid & 255);
    float v = (j < 256) ? attn_W[j*512 + k] : attn_W[(j-256)*512 + 256 + k];
    ((f16*)(ws+O_WQV))[gid] = (f16)(K2E * v);
    return;
  }
  gid -= 131072;
  if (gid < 524288){ ((f16*)(ws+O_W1))[gid] = (f16)l1_Wih[gid]; return; }
  gid -= 524288;
  if (gid < 524288){ ((f16*)(ws+O_W2))[gid] = (f16)l2_Wih[gid]; return; }
  gid -= 524288;
  if (gid < 262144){ ((f16*)(ws+O_WHH1))[gid] = (f16)l1_Whh[gid]; return; }
  gid -= 262144;
  if (gid < 262144){ ((f16*)(ws+O_WHH2))[gid] = (f16)l2_Whh[gid]; return; }
  gid -= 262144;
  if (gid < 512){ ((float*)(ws+O_BQV))[gid] = (gid < 256) ? 0.f : K2E*attn_b[gid-256]; return; }
  gid -= 512;
  if (gid < 1024){ ((float*)(ws+O_B1))[gid] = l1_bih[gid] + l1_bhh[gid]; return; }
  gid -= 1024;
  if (gid < 1024){ ((float*)(ws+O_B2))[gid] = l2_bih[gid] + l2_bhh[gid]; return; }
  gid -= 1024;
  if (gid < 256){ ((float*)(ws+O_V2))[gid] = -2.f*attn_V[gid]; return; }
  gid -= 256;
  if (gid < 8192){
    int j = (int)(gid & 7), slot = (int)(gid >> 3);
    int m = slot & 31, kgrp = (slot >> 5) & 3, kc = slot >> 7;
    int k = kc*32 + kgrp*8 + j;
    ((f16*)(ws+O_CPUB))[8192 + gid] = (f16)bcs[m*256 + k];
    return;
  }
  gid -= 8192;
  if (gid == 0){
    float s = 0.f;
    for (int h=0; h<256; h++) s += attn_V[h];
    *((float*)(ws+O_SUMV)) = s;
  }
}

// ============ enc f32 -> f16 ============
__global__ __launch_bounds__(256) void encf_kernel(const float* __restrict__ enc, char* __restrict__ ws){
  f16* dst = (f16*)(ws + O_ENCF);
  int i = (blockIdx.x*256 + threadIdx.x)*4;
  float4 v = *(const float4*)(enc + i);
  f16x4 o; o[0] = (f16)v.x; o[1] = (f16)v.y; o[2] = (f16)v.z; o[3] = (f16)v.w;
  *(f16x4*)(dst + i) = o;
}

// ============ NT GEMM: C[M,N](f32|f16) = A[M,256(+256)] * B[N,K]^T + bias =========
// A rows are 256 wide; optional A1 supplies k in [K0,K). 128x128 tile, BK=32, f16 MFMA.
template<bool CF16>
__global__ __launch_bounds__(256) void gemm_nt(const f16* __restrict__ A0, const f16* __restrict__ A1,
     int K0, const f16* __restrict__ B, int ldb, void* __restrict__ Cp, int ldc,
     int K, const float* __restrict__ bias)
{
  __shared__ f16 As[4096];
  __shared__ f16 Bs[4096];
  const int tid = threadIdx.x;
  const int lane = tid & 63;
  const int wave = tid >> 6;
  const int lm = lane & 15, kg = lane >> 4;
  const int mbase = blockIdx.y * 128;
  const int nbase = blockIdx.x * 128;
  const int wm = (wave >> 1) * 64, wn = (wave & 1) * 64;
  f32x4 acc[4][4];
#pragma unroll
  for (int i=0;i<4;i++)
#pragma unroll
    for (int j=0;j<4;j++) acc[i][j] = 0;
  const int r = tid >> 1, seg = tid & 1;
  for (int kc=0; kc<K; kc+=32){
    const f16* Ap = A0; int kk = kc;
    if (A1 && kc >= K0){ Ap = A1; kk = kc - K0; }
    {
      const f16* srcA = Ap + (size_t)(mbase + r)*256 + kk + seg*16;
      f16x8 va0 = *(const f16x8*)(srcA);
      f16x8 va1 = *(const f16x8*)(srcA + 8);
      *(f16x8*)&As[((seg*2+0)*128 + r)*8] = va0;
      *(f16x8*)&As[((seg*2+1)*128 + r)*8] = va1;
      const f16* srcB = B + (size_t)(nbase + r)*ldb + kc + seg*16;
      f16x8 vb0 = *(const f16x8*)(srcB);
      f16x8 vb1 = *(const f16x8*)(srcB + 8);
      *(f16x8*)&Bs[((seg*2+0)*128 + r)*8] = vb0;
      *(f16x8*)&Bs[((seg*2+1)*128 + r)*8] = vb1;
    }
    __syncthreads();
    f16x8 af[4], bfr[4];
#pragma unroll
    for (int i=0;i<4;i++) af[i]  = *(const f16x8*)&As[(kg*128 + wm + i*16 + lm)*8];
#pragma unroll
    for (int j=0;j<4;j++) bfr[j] = *(const f16x8*)&Bs[(kg*128 + wn + j*16 + lm)*8];
#pragma unroll
    for (int i=0;i<4;i++)
#pragma unroll
      for (int j=0;j<4;j++)
        acc[i][j] = __builtin_amdgcn_mfma_f32_16x16x32_f16(af[i], bfr[j], acc[i][j], 0,0,0);
    __syncthreads();
  }
#pragma unroll
  for (int i=0;i<4;i++){
#pragma unroll
    for (int j=0;j<4;j++){
      int col = nbase + wn + j*16 + lm;
      float bv = bias ? bias[col] : 0.f;
#pragma unroll
      for (int rr=0;rr<4;rr++){
        int row = mbase + wm + i*16 + kg*4 + rr;
        float v = acc[i][j][rr] + bv;
        if (CF16) ((f16*)Cp)[(size_t)row*ldc + col] = (f16)v;
        else      ((float*)Cp)[(size_t)row*ldc + col] = v;
      }
    }
  }
}

// ============ fused attention scores + softmax + ctx ============
// block = (b, 8 t's). scores via exact exp2 tanh; probs stay f32 in LDS; ctx f32-accum -> f16.
__global__ __launch_bounds__(256) void score_ctx_kernel(char* __restrict__ ws,
     const float* __restrict__ enc, const int* __restrict__ inp_len)
{
  __shared__ float s_pq[8][260];
  __shared__ float s_pv[32][260];
  __shared__ float s_sc[8][512];
  __shared__ float s_v2[256];
  __shared__ float s_sv[1];
  const int tid = threadIdx.x;
  const int b = blockIdx.y;
  const int t0 = blockIdx.x * 8;
  const float* pqv = (const float*)(ws + O_PQV);
  f16* ctx = (f16*)(ws + O_CTX);
  const int len = inp_len[b];
  {
    int row = tid >> 5, cb = (tid & 31) * 8;
    const float* src = pqv + (size_t)(b*512 + t0 + row)*512 + cb;
    *(float4*)&s_pq[row][cb]   = *(const float4*)(src);
    *(float4*)&s_pq[row][cb+4] = *(const float4*)(src+4);
    s_v2[tid] = ((const float*)(ws + O_V2))[tid];
    if (tid == 0) s_sv[0] = *((const float*)(ws + O_SUMV));
  }
  const int tt = tid >> 5;
  const int ss2 = tid & 31;
  for (int st=0; st<16; st++){
    {
      int row = tid >> 3, cb = (tid & 7) * 32;
      const float* src = pqv + (size_t)(b*512 + st*32 + row)*512 + 256 + cb;
#pragma unroll
      for (int c=0;c<32;c+=4) *(float4*)&s_pv[row][cb+c] = *(const float4*)(src+c);
    }
    __syncthreads();
    float a0=0.f,a1=0.f,a2=0.f,a3=0.f;
#pragma unroll 8
    for (int h=0;h<256;h+=4){
      float4 q = *(const float4*)&s_pq[tt][h];
      float4 p = *(const float4*)&s_pv[ss2][h];
      float4 w = *(const float4*)&s_v2[h];
      float e0 = __builtin_amdgcn_exp2f(q.x+p.x);
      float e1 = __builtin_amdgcn_exp2f(q.y+p.y);
      float e2 = __builtin_amdgcn_exp2f(q.z+p.z);
      float e3 = __builtin_amdgcn_exp2f(q.w+p.w);
      a0 += w.x * __builtin_amdgcn_rcpf(1.f+e0);
      a1 += w.y * __builtin_amdgcn_rcpf(1.f+e1);
      a2 += w.z * __builtin_amdgcn_rcpf(1.f+e2);
      a3 += w.w * __builtin_amdgcn_rcpf(1.f+e3);
    }
    int s = st*32 + ss2;
    float sc = s_sv[0] + ((a0+a1)+(a2+a3));
    if (s >= len) sc = -1.0e9f;
    s_sc[tt][s] = sc;
    __syncthreads();
  }
  {
    float m = -3.0e38f;
#pragma unroll
    for (int k2=0;k2<16;k2++) m = fmaxf(m, s_sc[tt][ss2 + 32*k2]);
#pragma unroll
    for (int off=16; off>=1; off>>=1) m = fmaxf(m, __shfl_xor(m, off, 64));
    float sum = 0.f;
    float ebuf[16];
#pragma unroll
    for (int k2=0;k2<16;k2++){
      float e = __builtin_amdgcn_exp2f((s_sc[tt][ss2+32*k2] - m) * L2E);
      ebuf[k2] = e; sum += e;
    }
#pragma unroll
    for (int off=16; off>=1; off>>=1) sum += __shfl_xor(sum, off, 64);
    float rinv = __builtin_amdgcn_rcpf(sum);
#pragma unroll
    for (int k2=0;k2<16;k2++) s_sc[tt][ss2+32*k2] = ebuf[k2]*rinv;
  }
  __syncthreads();
  float acc[8] = {0,0,0,0,0,0,0,0};
  const int hg = tid & 31;
  for (int st=0; st<16; st++){
    {
      int row = tid >> 3, cb = (tid & 7)*32;
      const float* src = enc + (size_t)(b*512 + st*32 + row)*256 + cb;
#pragma unroll
      for (int c=0;c<32;c+=4) *(float4*)&s_pv[row][cb+c] = *(const float4*)(src+c);
    }
    __syncthreads();
#pragma unroll 4
    for (int si=0; si<32; si++){
      float a = s_sc[tt][st*32+si];
#pragma unroll
      for (int u=0;u<8;u++) acc[u] += a * s_pv[si][hg + 32*u];
    }
    __syncthreads();
  }
#pragma unroll
  for (int u=0;u<8;u++)
    ctx[(size_t)(b*512 + t0 + tt)*256 + hg + 32*u] = (f16)acc[u];
}

// ============ recurrences: 16 blocks layer-1 + 16 blocks layer-2, flag-pipelined ========
__global__ __launch_bounds__(256) void rec_kernel(char* __restrict__ ws,
        const float* __restrict__ bhs, const int* __restrict__ inp_len,
        float* __restrict__ out)
{
  __shared__ float s_g[4][32][16];
  const int tid = threadIdx.x;
  const int lane = tid & 63;
  const int wave = tid >> 6;
  const int lm = lane & 15;
  const int kg = lane >> 4;
  int* flag1 = (int*)(ws + O_FLAGS);
  int* flag2 = flag1 + 512;
  f16* cpub  = (f16*)(ws + O_CPUB);
  f16* h2pub = (f16*)(ws + O_H2PUB);
  f16* decp  = (f16*)(ws + O_DECH);
  const int b0 = tid >> 4;
  const int kl = tid & 15;

  if (blockIdx.x < 16) {
    // ---- layer 1 (note reference quirk: matmul uses carry c; c_new = f*h_prev + i*g~)
    const int isl = blockIdx.x;
    const f16* whh1 = (const f16*)(ws + O_WHH1);
    const f16* gih1 = (const f16*)(ws + O_GIH1);
    f16x8 bf[8];
    {
      int j = wave*256 + isl*16 + lm;
#pragma unroll
      for (int kc=0;kc<8;kc++) bf[kc] = *(const f16x8*)(whh1 + j*256 + kc*32 + kg*8);
    }
    float h_loc[2];
    h_loc[0] = bhs[b0*256 + isl*16 + kl];
    h_loc[1] = bhs[(b0+16)*256 + isl*16 + kl];
    const int kk = isl*16 + kl;
    const int ppos = (((kk>>5)<<7) + (((kk>>3)&3)<<5))*8 + (kk&7);
    for (int t=0;t<512;t++){
      if (t > 0){
        if (tid==0){ while (__hip_atomic_load(&flag1[t-1], __ATOMIC_RELAXED, __HIP_MEMORY_SCOPE_AGENT) < 16) __builtin_amdgcn_s_sleep(1); }
        __syncthreads();
        __builtin_amdgcn_fence(__ATOMIC_ACQUIRE, "agent");
      }
      const f16* cp = cpub + (((t+1)&1)<<13);
      f32x4 acc0 = 0, acc1 = 0;
#pragma unroll
      for (int kc=0;kc<8;kc++){
        f16x8 a0 = *(const f16x8*)(cp + ((kc<<7) + (kg<<5) + lm)*8);
        f16x8 a1 = *(const f16x8*)(cp + ((kc<<7) + (kg<<5) + 16 + lm)*8);
        acc0 = __builtin_amdgcn_mfma_f32_16x16x32_f16(a0, bf[kc], acc0, 0,0,0);
        acc1 = __builtin_amdgcn_mfma_f32_16x16x32_f16(a1, bf[kc], acc1, 0,0,0);
      }
#pragma unroll
      for (int rr=0;rr<4;rr++){
        s_g[wave][kg*4+rr][lm] = acc0[rr];
        s_g[wave][16+kg*4+rr][lm] = acc1[rr];
      }
      __syncthreads();
#pragma unroll
      for (int x=0;x<2;x++){
        int b = b0 + x*16;
        int grow = (b*512 + t)*1024 + isl*16 + kl;
        float gi = s_g[0][b][kl] + (float)gih1[grow];
        float gf = s_g[1][b][kl] + (float)gih1[grow+256];
        float gc = s_g[2][b][kl] + (float)gih1[grow+512];
        float go = s_g[3][b][kl] + (float)gih1[grow+768];
        float ig = fast_sigmoid(gi), fg = fast_sigmoid(gf);
        float cc = fast_tanh(gc),   og = fast_sigmoid(go);
        float cn = fg*h_loc[x] + ig*cc;      // quirk: additive path is h_prev
        float hn = og*fast_tanh(cn);
        h_loc[x] = hn;
        int pos = ppos + (b<<3);
        cpub[((t&1)<<13) + pos] = (f16)cn;
        decp[(t<<13) + pos] = (f16)hn;
      }
      __threadfence();
      __syncthreads();
      if (tid==0) __hip_atomic_fetch_add(&flag1[t], 1, __ATOMIC_RELEASE, __HIP_MEMORY_SCOPE_AGENT);
    }
  } else {
    // ---- layer 2 (standard cell, masked freeze)
    const int isl = blockIdx.x - 16;
    const f16* whh2 = (const f16*)(ws + O_WHH2);
    const f16* w2   = (const f16*)(ws + O_W2);
    const f16* gih2 = (const f16*)(ws + O_GIH2C);
    f16x8 bfh[8], bfx[8];
    {
      int j = wave*256 + isl*16 + lm;
#pragma unroll
      for (int kc=0;kc<8;kc++){
        bfh[kc] = *(const f16x8*)(whh2 + j*256 + kc*32 + kg*8);
        bfx[kc] = *(const f16x8*)(w2 + j*512 + kc*32 + kg*8);
      }
    }
    float c_loc[2] = {0.f, 0.f};
    float h_loc[2] = {0.f, 0.f};
    int lenv[2]; lenv[0] = inp_len[b0]; lenv[1] = inp_len[b0+16];
    const int kk = isl*16 + kl;
    const int ppos = (((kk>>5)<<7) + (((kk>>3)&3)<<5))*8 + (kk&7);
    for (int t=0;t<512;t++){
      if (tid==0){
        while (__hip_atomic_load(&flag1[t], __ATOMIC_RELAXED, __HIP_MEMORY_SCOPE_AGENT) < 16) __builtin_amdgcn_s_sleep(1);
        if (t>0){ while (__hip_atomic_load(&flag2[t-1], __ATOMIC_RELAXED, __HIP_MEMORY_SCOPE_AGENT) < 16) __builtin_amdgcn_s_sleep(1); }
      }
      __syncthreads();
      __builtin_amdgcn_fence(__ATOMIC_ACQUIRE, "agent");
      const f16* xp = decp + (t<<13);
      const f16* hp = h2pub + (((t+1)&1)<<13);
      f32x4 acc0 = 0, acc1 = 0;
#pragma unroll
      for (int kc=0;kc<8;kc++){
        int off = ((kc<<7) + (kg<<5) + lm)*8;
        f16x8 ax0 = *(const f16x8*)(xp + off);
        f16x8 ax1 = *(const f16x8*)(xp + off + 128);
        f16x8 ah0 = *(const f16x8*)(hp + off);
        f16x8 ah1 = *(const f16x8*)(hp + off + 128);
        acc0 = __builtin_amdgcn_mfma_f32_16x16x32_f16(ax0, bfx[kc], acc0, 0,0,0);
        acc1 = __builtin_amdgcn_mfma_f32_16x16x32_f16(ax1, bfx[kc], acc1, 0,0,0);
        acc0 = __builtin_amdgcn_mfma_f32_16x16x32_f16(ah0, bfh[kc], acc0, 0,0,0);
        acc1 = __builtin_amdgcn_mfma_f32_16x16x32_f16(ah1, bfh[kc], acc1, 0,0,0);
      }
#pragma unroll
      for (int rr=0;rr<4;rr++){
        s_g[wave][kg*4+rr][lm] = acc0[rr];
        s_g[wave][16+kg*4+rr][lm] = acc1[rr];
      }
      __syncthreads();
#pragma unroll
      for (int x=0;x<2;x++){
        int b = b0 + x*16;
        int grow = (b*512 + t)*1024 + isl*16 + kl;
        float gi = s_g[0][b][kl] + (float)gih2[grow];
        float gf = s_g[1][b][kl] + (float)gih2[grow+256];
        float gc = s_g[2][b][kl] + (float)gih2[grow+512];
        float go = s_g[3][b][kl] + (float)gih2[grow+768];
        float ig = fast_sigmoid(gi), fg = fast_sigmoid(gf);
        float cc = fast_tanh(gc),   og = fast_sigmoid(go);
        float cn = fg*c_loc[x] + ig*cc;
        float hn = og*fast_tanh(cn);
        bool valid = (t < lenv[x]);
        c_loc[x] = valid ? cn : c_loc[x];
        float hnew = valid ? hn : h_loc[x];
        h_loc[x] = hnew;
        out[(size_t)(b*512 + t)*256 + isl*16 + kl] = valid ? hn : 0.f;
        h2pub[((t&1)<<13) + ppos + (b<<3)] = (f16)hnew;
      }
      __threadfence();
      __syncthreads();
      if (tid==0) __hip_atomic_fetch_add(&flag2[t], 1, __ATOMIC_RELEASE, __HIP_MEMORY_SCOPE_AGENT);
    }
  }
}

extern "C" void kernel_launch(void* const* d_in, const int* in_sizes, int n_in,
                              void* d_out, int out_size, void* d_ws, size_t ws_size,
                              hipStream_t stream) {
  if (ws_size < WS_NEED) return;  // workspace too small; bail (output stays poison -> visible failure)
  const float* enc    = (const float*)d_in[0];
  const float* bhs    = (const float*)d_in[1];
  const float* bcs    = (const float*)d_in[2];
  const float* attn_W = (const float*)d_in[3];
  const float* attn_b = (const float*)d_in[4];
  const float* attn_V = (const float*)d_in[5];
  const float* l1_Wih = (const float*)d_in[6];
  const float* l1_Whh = (const float*)d_in[7];
  const float* l1_bih = (const float*)d_in[8];
  const float* l1_bhh = (const float*)d_in[9];
  const float* l2_Wih = (const float*)d_in[10];
  const float* l2_Whh = (const float*)d_in[11];
  const float* l2_bih = (const float*)d_in[12];
  const float* l2_bhh = (const float*)d_in[13];
  const int* inp_len  = (const int*)d_in[14];
  char* ws = (char*)d_ws;
  float* out = (float*)d_out;

  hipMemsetAsync(ws + O_CPUB, 0, (size_t)(O_FLAGS + 4096 - O_CPUB), stream);
  prep_kernel<<<6700, 256, 0, stream>>>(attn_W, attn_b, attn_V, l1_Wih, l1_Whh, l1_bih, l1_bhh,
                                        l2_Wih, l2_Whh, l2_bih, l2_bhh, bcs, ws);
  encf_kernel<<<4096, 256, 0, stream>>>(enc, ws);
  // pqv = k2*(enc@Wq^T | enc@Wv^T + b)
  gemm_nt<false><<<dim3(4,128), 256, 0, stream>>>((const f16*)(ws+O_ENCF), nullptr, 256,
        (const f16*)(ws+O_WQV), 256, (void*)(ws+O_PQV), 512, 256, (const float*)(ws+O_BQV));
  score_ctx_kernel<<<dim3(64,32), 256, 0, stream>>>(ws, enc, inp_len);
  // gih1 = [enc|ctx]@W1^T + (bih1+bhh1)
  gemm_nt<true><<<dim3(8,128), 256, 0, stream>>>((const f16*)(ws+O_ENCF), (const f16*)(ws+O_CTX), 256,
        (const f16*)(ws+O_W1), 512, (void*)(ws+O_GIH1), 1024, 512, (const float*)(ws+O_B1));
  // gih2c = ctx@W2R^T + (bih2+bhh2)   (aliases pqv region; pqv dead after score_ctx)
  gemm_nt<true><<<dim3(8,128), 256, 0, stream>>>((const f16*)(ws+O_CTX), nullptr, 256,
        (const f16*)(ws+O_W2)+256, 512, (void*)(ws+O_GIH2C), 1024, 256, (const float*)(ws+O_B2));
  rec_kernel<<<32, 256, 0, stream>>>(ws, bhs, inp_len, out);
}

// Round 2
// 3718.058 us; speedup vs baseline: 1.6196x; 1.6196x over previous
//
#include <hip/hip_runtime.h>

typedef _Float16 f16;
typedef _Float16 f16x2 __attribute__((ext_vector_type(2)));
typedef _Float16 f16x8 __attribute__((ext_vector_type(8)));
typedef _Float16 f16x4 __attribute__((ext_vector_type(4)));
typedef float f32x4 __attribute__((ext_vector_type(4)));

#define L2E 1.4426950408889634f
#define K2E 2.8853900817779268f

// ---- workspace layout (bytes). total 95,764,480 (~95.8 MB)
#define O_PQV   0UL            // f32 [16384][512]  (aliased by GIH2C later)
#define O_GIH2C 0UL            // f16 [16384][1024]
#define O_CTX   33554432UL     // f16 [16384][256]
#define O_ENCF  41943040UL     // f16 [16384][256]
#define O_GIH1  50331648UL     // f16 [16384][1024]
#define O_DECH  83886080UL     // f16 [512][8192] frag-order
#define O_WQV   92274688UL     // f16 [512][256]
#define O_W1    92536832UL     // f16 [1024][512]
#define O_W2    93585408UL     // f16 [1024][512]
#define O_WHH1  94633984UL     // f16 [1024][256]
#define O_WHH2  95158272UL     // f16 [1024][256]
#define O_BQV   95682560UL     // f32 [512]
#define O_B1    95684608UL     // f32 [1024]
#define O_B2    95688704UL     // f32 [1024]
#define O_V2    95692800UL     // f32 [256]  (= -2*V)
#define O_SUMV  95693824UL     // f32 [1]
#define O_CPUB  95694848UL     // f16 [2][8192] frag-order c publish
#define O_H2PUB 95727616UL     // f16 [2][8192]
#define O_FLAGS 95760384UL     // int pflag1[16], pflag2[16]
#define WS_NEED 95764480UL

__device__ __forceinline__ float fast_sigmoid(float x){
  float e = __builtin_amdgcn_exp2f(-L2E * x);
  return __builtin_amdgcn_rcpf(1.f + e);
}
__device__ __forceinline__ float fast_tanh(float x){
  float e = __builtin_amdgcn_exp2f(K2E * x);
  return 1.f - 2.f * __builtin_amdgcn_rcpf(1.f + e);
}

// coherent-point (sc0 sc1) helpers: write-through stores + L2-bypassing loads.
__device__ __forceinline__ void store_pair_wt(f16* p, float a, float b){
  union { unsigned int u; f16 h[2]; } v;
  v.h[0] = (f16)a; v.h[1] = (f16)b;
  __hip_atomic_store((unsigned int*)p, v.u, __ATOMIC_RELAXED, __HIP_MEMORY_SCOPE_AGENT);
}
__device__ __forceinline__ f16x8 load_a8_coh(const f16* p){
  unsigned long long* q = (unsigned long long*)p;
  unsigned long long a = __hip_atomic_load(q,     __ATOMIC_RELAXED, __HIP_MEMORY_SCOPE_AGENT);
  unsigned long long b = __hip_atomic_load(q + 1, __ATOMIC_RELAXED, __HIP_MEMORY_SCOPE_AGENT);
  f16x8 r;
  ((unsigned long long*)&r)[0] = a;
  ((unsigned long long*)&r)[1] = b;
  return r;
}

// wave-0 polls per-producer flag slots in parallel; everyone else waits at barrier.
__device__ __forceinline__ void wait_flags(int* f1, int thr1, int* f2, int thr2, int tid){
  if (tid < 64){
    int* addr = nullptr; int thr = 0; bool ok = true;
    if (tid < 16){ addr = &f1[tid]; thr = thr1; ok = false; }
    else if (f2 != nullptr && tid < 32){ addr = &f2[tid - 16]; thr = thr2; ok = false; }
    while (true){
      if (!ok) ok = (__hip_atomic_load(addr, __ATOMIC_RELAXED, __HIP_MEMORY_SCOPE_AGENT) >= thr);
      if (__all((int)ok)) break;
      __builtin_amdgcn_s_sleep(2);
    }
  }
  __syncthreads();
}

// producer: all publish stores are write-through; ack them, barrier, then relaxed flag store.
__device__ __forceinline__ void publish_done(int* slot, int val, int tid){
  asm volatile("s_waitcnt vmcnt(0)" ::: "memory");
  __syncthreads();
  if (tid == 0) __hip_atomic_store(slot, val, __ATOMIC_RELAXED, __HIP_MEMORY_SCOPE_AGENT);
}

// ============ prep: weight conversions, biases, cpub[1]=backward_cell_state =========
__global__ __launch_bounds__(256) void prep_kernel(
    const float* __restrict__ attn_W, const float* __restrict__ attn_b, const float* __restrict__ attn_V,
    const float* __restrict__ l1_Wih, const float* __restrict__ l1_Whh,
    const float* __restrict__ l1_bih, const float* __restrict__ l1_bhh,
    const float* __restrict__ l2_Wih, const float* __restrict__ l2_Whh,
    const float* __restrict__ l2_bih, const float* __restrict__ l2_bhh,
    const float* __restrict__ bcs, char* __restrict__ ws)
{
  long gid = (long)blockIdx.x*256 + threadIdx.x;
  if (gid < 131072){
    int j = (int)(gid >> 8), k = (int)(gid & 255);
    float v = (j < 256) ? attn_W[j*512 + k] : attn_W[(j-256)*512 + 256 + k];
    ((f16*)(ws+O_WQV))[gid] = (f16)(K2E * v);
    return;
  }
  gid -= 131072;
  if (gid < 524288){ ((f16*)(ws+O_W1))[gid] = (f16)l1_Wih[gid]; return; }
  gid -= 524288;
  if (gid < 524288){ ((f16*)(ws+O_W2))[gid] = (f16)l2_Wih[gid]; return; }
  gid -= 524288;
  if (gid < 262144){ ((f16*)(ws+O_WHH1))[gid] = (f16)l1_Whh[gid]; return; }
  gid -= 262144;
  if (gid < 262144){ ((f16*)(ws+O_WHH2))[gid] = (f16)l2_Whh[gid]; return; }
  gid -= 262144;
  if (gid < 512){ ((float*)(ws+O_BQV))[gid] = (gid < 256) ? 0.f : K2E*attn_b[gid-256]; return; }
  gid -= 512;
  if (gid < 1024){ ((float*)(ws+O_B1))[gid] = l1_bih[gid] + l1_bhh[gid]; return; }
  gid -= 1024;
  if (gid < 1024){ ((float*)(ws+O_B2))[gid] = l2_bih[gid] + l2_bhh[gid]; return; }
  gid -= 1024;
  if (gid < 256){ ((float*)(ws+O_V2))[gid] = -2.f*attn_V[gid]; return; }
  gid -= 256;
  if (gid < 8192){
    int j = (int)(gid & 7), slot = (int)(gid >> 3);
    int m = slot & 31, kgrp = (slot >> 5) & 3, kc = slot >> 7;
    int k = kc*32 + kgrp*8 + j;
    ((f16*)(ws+O_CPUB))[8192 + gid] = (f16)bcs[m*256 + k];
    return;
  }
  gid -= 8192;
  if (gid == 0){
    float s = 0.f;
    for (int h=0; h<256; h++) s += attn_V[h];
    *((float*)(ws+O_SUMV)) = s;
  }
}

// ============ enc f32 -> f16 ============
__global__ __launch_bounds__(256) void encf_kernel(const float* __restrict__ enc, char* __restrict__ ws){
  f16* dst = (f16*)(ws + O_ENCF);
  int i = (blockIdx.x*256 + threadIdx.x)*4;
  float4 v = *(const float4*)(enc + i);
  f16x4 o; o[0] = (f16)v.x; o[1] = (f16)v.y; o[2] = (f16)v.z; o[3] = (f16)v.w;
  *(f16x4*)(dst + i) = o;
}

// ============ NT GEMM: C[M,N](f32|f16) = A[M,256(+256)] * B[N,K]^T + bias =========
template<bool CF16>
__global__ __launch_bounds__(256) void gemm_nt(const f16* __restrict__ A0, const f16* __restrict__ A1,
     int K0, const f16* __restrict__ B, int ldb, void* __restrict__ Cp, int ldc,
     int K, const float* __restrict__ bias)
{
  __shared__ f16 As[4096];
  __shared__ f16 Bs[4096];
  const int tid = threadIdx.x;
  const int lane = tid & 63;
  const int wave = tid >> 6;
  const int lm = lane & 15, kg = lane >> 4;
  const int mbase = blockIdx.y * 128;
  const int nbase = blockIdx.x * 128;
  const int wm = (wave >> 1) * 64, wn = (wave & 1) * 64;
  f32x4 acc[4][4];
#pragma unroll
  for (int i=0;i<4;i++)
#pragma unroll
    for (int j=0;j<4;j++) acc[i][j] = 0;
  const int r = tid >> 1, seg = tid & 1;
  for (int kc=0; kc<K; kc+=32){
    const f16* Ap = A0; int kk = kc;
    if (A1 && kc >= K0){ Ap = A1; kk = kc - K0; }
    {
      const f16* srcA = Ap + (size_t)(mbase + r)*256 + kk + seg*16;
      f16x8 va0 = *(const f16x8*)(srcA);
      f16x8 va1 = *(const f16x8*)(srcA + 8);
      *(f16x8*)&As[((seg*2+0)*128 + r)*8] = va0;
      *(f16x8*)&As[((seg*2+1)*128 + r)*8] = va1;
      const f16* srcB = B + (size_t)(nbase + r)*ldb + kc + seg*16;
      f16x8 vb0 = *(const f16x8*)(srcB);
      f16x8 vb1 = *(const f16x8*)(srcB + 8);
      *(f16x8*)&Bs[((seg*2+0)*128 + r)*8] = vb0;
      *(f16x8*)&Bs[((seg*2+1)*128 + r)*8] = vb1;
    }
    __syncthreads();
    f16x8 af[4], bfr[4];
#pragma unroll
    for (int i=0;i<4;i++) af[i]  = *(const f16x8*)&As[(kg*128 + wm + i*16 + lm)*8];
#pragma unroll
    for (int j=0;j<4;j++) bfr[j] = *(const f16x8*)&Bs[(kg*128 + wn + j*16 + lm)*8];
#pragma unroll
    for (int i=0;i<4;i++)
#pragma unroll
      for (int j=0;j<4;j++)
        acc[i][j] = __builtin_amdgcn_mfma_f32_16x16x32_f16(af[i], bfr[j], acc[i][j], 0,0,0);
    __syncthreads();
  }
#pragma unroll
  for (int i=0;i<4;i++){
#pragma unroll
    for (int j=0;j<4;j++){
      int col = nbase + wn + j*16 + lm;
      float bv = bias ? bias[col] : 0.f;
#pragma unroll
      for (int rr=0;rr<4;rr++){
        int row = mbase + wm + i*16 + kg*4 + rr;
        float v = acc[i][j][rr] + bv;
        if (CF16) ((f16*)Cp)[(size_t)row*ldc + col] = (f16)v;
        else      ((float*)Cp)[(size_t)row*ldc + col] = v;
      }
    }
  }
}

// ============ fused attention scores + softmax + ctx ============
__global__ __launch_bounds__(256) void score_ctx_kernel(char* __restrict__ ws,
     const float* __restrict__ enc, const int* __restrict__ inp_len)
{
  __shared__ float s_pq[8][260];
  __shared__ float s_pv[32][260];
  __shared__ float s_sc[8][512];
  __shared__ float s_v2[256];
  __shared__ float s_sv[1];
  const int tid = threadIdx.x;
  const int b = blockIdx.y;
  const int t0 = blockIdx.x * 8;
  const float* pqv = (const float*)(ws + O_PQV);
  f16* ctx = (f16*)(ws + O_CTX);
  const int len = inp_len[b];
  {
    int row = tid >> 5, cb = (tid & 31) * 8;
    const float* src = pqv + (size_t)(b*512 + t0 + row)*512 + cb;
    *(float4*)&s_pq[row][cb]   = *(const float4*)(src);
    *(float4*)&s_pq[row][cb+4] = *(const float4*)(src+4);
    s_v2[tid] = ((const float*)(ws + O_V2))[tid];
    if (tid == 0) s_sv[0] = *((const float*)(ws + O_SUMV));
  }
  const int tt = tid >> 5;
  const int ss2 = tid & 31;
  for (int st=0; st<16; st++){
    {
      int row = tid >> 3, cb = (tid & 7) * 32;
      const float* src = pqv + (size_t)(b*512 + st*32 + row)*512 + 256 + cb;
#pragma unroll
      for (int c=0;c<32;c+=4) *(float4*)&s_pv[row][cb+c] = *(const float4*)(src+c);
    }
    __syncthreads();
    float a0=0.f,a1=0.f,a2=0.f,a3=0.f;
#pragma unroll 8
    for (int h=0;h<256;h+=4){
      float4 q = *(const float4*)&s_pq[tt][h];
      float4 p = *(const float4*)&s_pv[ss2][h];
      float4 w = *(const float4*)&s_v2[h];
      float e0 = __builtin_amdgcn_exp2f(q.x+p.x);
      float e1 = __builtin_amdgcn_exp2f(q.y+p.y);
      float e2 = __builtin_amdgcn_exp2f(q.z+p.z);
      float e3 = __builtin_amdgcn_exp2f(q.w+p.w);
      a0 += w.x * __builtin_amdgcn_rcpf(1.f+e0);
      a1 += w.y * __builtin_amdgcn_rcpf(1.f+e1);
      a2 += w.z * __builtin_amdgcn_rcpf(1.f+e2);
      a3 += w.w * __builtin_amdgcn_rcpf(1.f+e3);
    }
    int s = st*32 + ss2;
    float sc = s_sv[0] + ((a0+a1)+(a2+a3));
    if (s >= len) sc = -1.0e9f;
    s_sc[tt][s] = sc;
    __syncthreads();
  }
  {
    float m = -3.0e38f;
#pragma unroll
    for (int k2=0;k2<16;k2++) m = fmaxf(m, s_sc[tt][ss2 + 32*k2]);
#pragma unroll
    for (int off=16; off>=1; off>>=1) m = fmaxf(m, __shfl_xor(m, off, 64));
    float sum = 0.f;
    float ebuf[16];
#pragma unroll
    for (int k2=0;k2<16;k2++){
      float e = __builtin_amdgcn_exp2f((s_sc[tt][ss2+32*k2] - m) * L2E);
      ebuf[k2] = e; sum += e;
    }
#pragma unroll
    for (int off=16; off>=1; off>>=1) sum += __shfl_xor(sum, off, 64);
    float rinv = __builtin_amdgcn_rcpf(sum);
#pragma unroll
    for (int k2=0;k2<16;k2++) s_sc[tt][ss2+32*k2] = ebuf[k2]*rinv;
  }
  __syncthreads();
  float acc[8] = {0,0,0,0,0,0,0,0};
  const int hg = tid & 31;
  for (int st=0; st<16; st++){
    {
      int row = tid >> 3, cb = (tid & 7)*32;
      const float* src = enc + (size_t)(b*512 + st*32 + row)*256 + cb;
#pragma unroll
      for (int c=0;c<32;c+=4) *(float4*)&s_pv[row][cb+c] = *(const float4*)(src+c);
    }
    __syncthreads();
#pragma unroll 4
    for (int si=0; si<32; si++){
      float a = s_sc[tt][st*32+si];
#pragma unroll
      for (int u=0;u<8;u++) acc[u] += a * s_pv[si][hg + 32*u];
    }
    __syncthreads();
  }
#pragma unroll
  for (int u=0;u<8;u++)
    ctx[(size_t)(b*512 + t0 + tt)*256 + hg + 32*u] = (f16)acc[u];
}

// ============ recurrences: 16 blocks layer-1 + 16 blocks layer-2 ============
// fence-free pipeline: write-through publishes + per-producer flag slots + parallel polls.
__global__ __launch_bounds__(256) void rec_kernel(char* __restrict__ ws,
        const float* __restrict__ bhs, const int* __restrict__ inp_len,
        float* __restrict__ out)
{
  __shared__ float s_g[4][32][16];
  const int tid = threadIdx.x;
  const int lane = tid & 63;
  const int wave = tid >> 6;
  const int lm = lane & 15;
  const int kg = lane >> 4;
  int* pflag1 = (int*)(ws + O_FLAGS);
  int* pflag2 = pflag1 + 16;
  f16* cpub  = (f16*)(ws + O_CPUB);
  f16* h2pub = (f16*)(ws + O_H2PUB);
  f16* decp  = (f16*)(ws + O_DECH);
  // gate-phase mapping: one batch, two adjacent k-components per thread
  const int b  = tid >> 3;
  const int kp = tid & 7;
  const int kl0 = kp*2, kl1 = kp*2 + 1;

  if (blockIdx.x < 16) {
    // ---- layer 1 (reference quirk: matmul uses carry c; c_new = f*h_prev + i*g~)
    const int isl = blockIdx.x;
    const f16* whh1 = (const f16*)(ws + O_WHH1);
    const f16* gih1 = (const f16*)(ws + O_GIH1);
    f16x8 bf[8];
    {
      int j = wave*256 + isl*16 + lm;
#pragma unroll
      for (int kc=0;kc<8;kc++) bf[kc] = *(const f16x8*)(whh1 + j*256 + kc*32 + kg*8);
    }
    float h0 = bhs[b*256 + isl*16 + kl0];
    float h1 = bhs[b*256 + isl*16 + kl1];
    const int kk0 = isl*16 + kl0;
    const int ppos = (((kk0>>5)<<7) + (((kk0>>3)&3)<<5))*8 + (kk0&7) + (b<<3);
    for (int t=0;t<512;t++){
      // prefetch gih (plain cached loads, address depends only on t)
      const f16* gp = gih1 + (size_t)(b*512 + t)*1024 + isl*16 + kl0;
      f16x2 gv0 = *(const f16x2*)(gp);
      f16x2 gv1 = *(const f16x2*)(gp+256);
      f16x2 gv2 = *(const f16x2*)(gp+512);
      f16x2 gv3 = *(const f16x2*)(gp+768);
      wait_flags(pflag1, t, nullptr, 0, tid);
      const f16* cp = cpub + (((t+1)&1)<<13);
      f32x4 acc0 = 0, acc1 = 0;
#pragma unroll
      for (int kc=0;kc<8;kc++){
        f16x8 a0 = load_a8_coh(cp + ((kc<<7) + (kg<<5) + lm)*8);
        f16x8 a1 = load_a8_coh(cp + ((kc<<7) + (kg<<5) + 16 + lm)*8);
        acc0 = __builtin_amdgcn_mfma_f32_16x16x32_f16(a0, bf[kc], acc0, 0,0,0);
        acc1 = __builtin_amdgcn_mfma_f32_16x16x32_f16(a1, bf[kc], acc1, 0,0,0);
      }
#pragma unroll
      for (int rr=0;rr<4;rr++){
        s_g[wave][kg*4+rr][lm] = acc0[rr];
        s_g[wave][16+kg*4+rr][lm] = acc1[rr];
      }
      __syncthreads();
      {
        float gi0 = s_g[0][b][kl0] + (float)gv0[0];
        float gi1 = s_g[0][b][kl1] + (float)gv0[1];
        float gf0 = s_g[1][b][kl0] + (float)gv1[0];
        float gf1 = s_g[1][b][kl1] + (float)gv1[1];
        float gc0 = s_g[2][b][kl0] + (float)gv2[0];
        float gc1 = s_g[2][b][kl1] + (float)gv2[1];
        float go0 = s_g[3][b][kl0] + (float)gv3[0];
        float go1 = s_g[3][b][kl1] + (float)gv3[1];
        float cn0 = fast_sigmoid(gf0)*h0 + fast_sigmoid(gi0)*fast_tanh(gc0);  // quirk
        float cn1 = fast_sigmoid(gf1)*h1 + fast_sigmoid(gi1)*fast_tanh(gc1);
        float hn0 = fast_sigmoid(go0)*fast_tanh(cn0);
        float hn1 = fast_sigmoid(go1)*fast_tanh(cn1);
        h0 = hn0; h1 = hn1;
        store_pair_wt(cpub + ((t&1)<<13) + ppos, cn0, cn1);
        store_pair_wt(decp + (t<<13) + ppos, hn0, hn1);
      }
      publish_done(&pflag1[isl], t+1, tid);
    }
  } else {
    // ---- layer 2 (standard cell, masked freeze)
    const int isl = blockIdx.x - 16;
    const f16* whh2 = (const f16*)(ws + O_WHH2);
    const f16* w2   = (const f16*)(ws + O_W2);
    const f16* gih2 = (const f16*)(ws + O_GIH2C);
    f16x8 bfh[8], bfx[8];
    {
      int j = wave*256 + isl*16 + lm;
#pragma unroll
      for (int kc=0;kc<8;kc++){
        bfh[kc] = *(const f16x8*)(whh2 + j*256 + kc*32 + kg*8);
        bfx[kc] = *(const f16x8*)(w2 + j*512 + kc*32 + kg*8);
      }
    }
    float c0 = 0.f, c1 = 0.f, hh0 = 0.f, hh1 = 0.f;
    const int lenv = inp_len[b];
    const int kk0 = isl*16 + kl0;
    const int ppos = (((kk0>>5)<<7) + (((kk0>>3)&3)<<5))*8 + (kk0&7) + (b<<3);
    for (int t=0;t<512;t++){
      const f16* gp = gih2 + (size_t)(b*512 + t)*1024 + isl*16 + kl0;
      f16x2 gv0 = *(const f16x2*)(gp);
      f16x2 gv1 = *(const f16x2*)(gp+256);
      f16x2 gv2 = *(const f16x2*)(gp+512);
      f16x2 gv3 = *(const f16x2*)(gp+768);
      wait_flags(pflag1, t+1, pflag2, t, tid);
      const f16* xp = decp + (t<<13);
      const f16* hp = h2pub + (((t+1)&1)<<13);
      f32x4 acc0 = 0, acc1 = 0;
#pragma unroll
      for (int kc=0;kc<8;kc++){
        int off = ((kc<<7) + (kg<<5) + lm)*8;
        f16x8 ax0 = load_a8_coh(xp + off);
        f16x8 ax1 = load_a8_coh(xp + off + 128);
        f16x8 ah0 = load_a8_coh(hp + off);
        f16x8 ah1 = load_a8_coh(hp + off + 128);
        acc0 = __builtin_amdgcn_mfma_f32_16x16x32_f16(ax0, bfx[kc], acc0, 0,0,0);
        acc1 = __builtin_amdgcn_mfma_f32_16x16x32_f16(ax1, bfx[kc], acc1, 0,0,0);
        acc0 = __builtin_amdgcn_mfma_f32_16x16x32_f16(ah0, bfh[kc], acc0, 0,0,0);
        acc1 = __builtin_amdgcn_mfma_f32_16x16x32_f16(ah1, bfh[kc], acc1, 0,0,0);
      }
#pragma unroll
      for (int rr=0;rr<4;rr++){
        s_g[wave][kg*4+rr][lm] = acc0[rr];
        s_g[wave][16+kg*4+rr][lm] = acc1[rr];
      }
      __syncthreads();
      {
        float gi0 = s_g[0][b][kl0] + (float)gv0[0];
        float gi1 = s_g[0][b][kl1] + (float)gv0[1];
        float gf0 = s_g[1][b][kl0] + (float)gv1[0];
        float gf1 = s_g[1][b][kl1] + (float)gv1[1];
        float gc0 = s_g[2][b][kl0] + (float)gv2[0];
        float gc1 = s_g[2][b][kl1] + (float)gv2[1];
        float go0 = s_g[3][b][kl0] + (float)gv3[0];
        float go1 = s_g[3][b][kl1] + (float)gv3[1];
        float cn0 = fast_sigmoid(gf0)*c0 + fast_sigmoid(gi0)*fast_tanh(gc0);
        float cn1 = fast_sigmoid(gf1)*c1 + fast_sigmoid(gi1)*fast_tanh(gc1);
        float hn0 = fast_sigmoid(go0)*fast_tanh(cn0);
        float hn1 = fast_sigmoid(go1)*fast_tanh(cn1);
        bool valid = (t < lenv);
        c0 = valid ? cn0 : c0;
        c1 = valid ? cn1 : c1;
        hh0 = valid ? hn0 : hh0;
        hh1 = valid ? hn1 : hh1;
        float2 ov; ov.x = valid ? hn0 : 0.f; ov.y = valid ? hn1 : 0.f;
        *(float2*)(out + (size_t)(b*512 + t)*256 + isl*16 + kl0) = ov;  // plain cached store
        store_pair_wt(h2pub + ((t&1)<<13) + ppos, hh0, hh1);
      }
      publish_done(&pflag2[isl], t+1, tid);
    }
  }
}

extern "C" void kernel_launch(void* const* d_in, const int* in_sizes, int n_in,
                              void* d_out, int out_size, void* d_ws, size_t ws_size,
                              hipStream_t stream) {
  if (ws_size < WS_NEED) return;  // workspace too small; bail (output stays poison -> visible failure)
  const float* enc    = (const float*)d_in[0];
  const float* bhs    = (const float*)d_in[1];
  const float* bcs    = (const float*)d_in[2];
  const float* attn_W = (const float*)d_in[3];
  const float* attn_b = (const float*)d_in[4];
  const float* attn_V = (const float*)d_in[5];
  const float* l1_Wih = (const float*)d_in[6];
  const float* l1_Whh = (const float*)d_in[7];
  const float* l1_bih = (const float*)d_in[8];
  const float* l1_bhh = (const float*)d_in[9];
  const float* l2_Wih = (const float*)d_in[10];
  const float* l2_Whh = (const float*)d_in[11];
  const float* l2_bih = (const float*)d_in[12];
  const float* l2_bhh = (const float*)d_in[13];
  const int* inp_len  = (const int*)d_in[14];
  char* ws = (char*)d_ws;
  float* out = (float*)d_out;

  hipMemsetAsync(ws + O_CPUB, 0, (size_t)(O_FLAGS + 4096 - O_CPUB), stream);
  prep_kernel<<<6700, 256, 0, stream>>>(attn_W, attn_b, attn_V, l1_Wih, l1_Whh, l1_bih, l1_bhh,
                                        l2_Wih, l2_Whh, l2_bih, l2_bhh, bcs, ws);
  encf_kernel<<<4096, 256, 0, stream>>>(enc, ws);
  // pqv = k2*(enc@Wq^T | enc@Wv^T + b)
  gemm_nt<false><<<dim3(4,128), 256, 0, stream>>>((const f16*)(ws+O_ENCF), nullptr, 256,
        (const f16*)(ws+O_WQV), 256, (void*)(ws+O_PQV), 512, 256, (const float*)(ws+O_BQV));
  score_ctx_kernel<<<dim3(64,32), 256, 0, stream>>>(ws, enc, inp_len);
  // gih1 = [enc|ctx]@W1^T + (bih1+bhh1)
  gemm_nt<true><<<dim3(8,128), 256, 0, stream>>>((const f16*)(ws+O_ENCF), (const f16*)(ws+O_CTX), 256,
        (const f16*)(ws+O_W1), 512, (void*)(ws+O_GIH1), 1024, 512, (const float*)(ws+O_B1));
  // gih2c = ctx@W2R^T + (bih2+bhh2)   (aliases pqv region; pqv dead after score_ctx)
  gemm_nt<true><<<dim3(8,128), 256, 0, stream>>>((const f16*)(ws+O_CTX), nullptr, 256,
        (const f16*)(ws+O_W2)+256, 512, (void*)(ws+O_GIH2C), 1024, 256, (const float*)(ws+O_B2));
  rec_kernel<<<32, 256, 0, stream>>>(ws, bhs, inp_len, out);
}

// Round 3
// 3120.219 us; speedup vs baseline: 1.9299x; 1.1916x over previous
//
#include <hip/hip_runtime.h>

typedef _Float16 f16;
typedef _Float16 f16x2 __attribute__((ext_vector_type(2)));
typedef _Float16 f16x8 __attribute__((ext_vector_type(8)));
typedef _Float16 f16x4 __attribute__((ext_vector_type(4)));
typedef float f32x4 __attribute__((ext_vector_type(4)));

#define L2E 1.4426950408889634f
#define K2E 2.8853900817779268f

// ---- workspace layout (bytes)
#define O_PQV   0UL            // f32 [16384][512]  (aliased by GIH2C later)
#define O_GIH2C 0UL            // f16 [16384][1024]
#define O_CTX   33554432UL     // f16 [16384][256]
#define O_ENCF  41943040UL     // f16 [16384][256]
#define O_GIH1  50331648UL     // f16 [16384][1024]
#define O_DECH  83886080UL     // f16 [512][8192] frag-order
#define O_WQV   92274688UL     // f16 [512][256]
#define O_W1    92536832UL     // f16 [1024][512]
#define O_W2    93585408UL     // f16 [1024][512]
#define O_WHH1  94633984UL     // f16 [1024][256]
#define O_WHH2  95158272UL     // f16 [1024][256]
#define O_BQV   95682560UL     // f32 [512]
#define O_B1    95684608UL     // f32 [1024]
#define O_B2    95688704UL     // f32 [1024]
#define O_V2    95692800UL     // f32 [256]  (= -2*V)
#define O_SUMV  95693824UL     // f32 [1]
#define O_CPUB  95694848UL     // f16 [2][8192] frag-order c publish
#define O_H2PUB 95727616UL     // f16 [2][8192]
#define O_FLAGS 95760384UL     // int[128][32]: 64 L1 wave-flags + 64 L2 wave-flags, 128B apart
#define WS_NEED 95776768UL

__device__ __forceinline__ float fast_sigmoid(float x){
  float e = __builtin_amdgcn_exp2f(-L2E * x);
  return __builtin_amdgcn_rcpf(1.f + e);
}
__device__ __forceinline__ float fast_tanh(float x){
  float e = __builtin_amdgcn_exp2f(K2E * x);
  return 1.f - 2.f * __builtin_amdgcn_rcpf(1.f + e);
}

// coherent-point helpers: write-through stores + L2-bypassing loads.
__device__ __forceinline__ void store_pair_wt(f16* p, float a, float b){
  union { unsigned int u; f16 h[2]; } v;
  v.h[0] = (f16)a; v.h[1] = (f16)b;
  __hip_atomic_store((unsigned int*)p, v.u, __ATOMIC_RELAXED, __HIP_MEMORY_SCOPE_AGENT);
}
__device__ __forceinline__ f16x8 load_a8_coh(const f16* p){
  unsigned long long* q = (unsigned long long*)p;
  unsigned long long a = __hip_atomic_load(q,     __ATOMIC_RELAXED, __HIP_MEMORY_SCOPE_AGENT);
  unsigned long long b = __hip_atomic_load(q + 1, __ATOMIC_RELAXED, __HIP_MEMORY_SCOPE_AGENT);
  f16x8 r;
  ((unsigned long long*)&r)[0] = a;
  ((unsigned long long*)&r)[1] = b;
  return r;
}

// wave-0's 64 lanes poll 64 per-wave flag slots (128B apart) in parallel; no sleep.
template<bool TWO>
__device__ __forceinline__ void wait_flags_pw(const int* f1, int thr1, const int* f2, int thr2, int tid){
  if (tid < 64){
    const int off = tid << 5;   // 32 ints = 128 B per slot
    while (true){
      bool ok = (__hip_atomic_load(f1 + off, __ATOMIC_RELAXED, __HIP_MEMORY_SCOPE_AGENT) >= thr1);
      if (TWO)
        ok = ok && (__hip_atomic_load(f2 + off, __ATOMIC_RELAXED, __HIP_MEMORY_SCOPE_AGENT) >= thr2);
      if (__all((int)ok)) break;
    }
  }
  __syncthreads();
}

// per-wave publish: ack own wave's WT stores, then fire this wave's flag. No barrier.
__device__ __forceinline__ void publish_wave(int* base, int slot, int val, int lane){
  asm volatile("s_waitcnt vmcnt(0)" ::: "memory");
  if (lane == 0)
    __hip_atomic_store(base + (slot << 5), val, __ATOMIC_RELAXED, __HIP_MEMORY_SCOPE_AGENT);
}

// ============ prep: weight conversions, biases, cpub[1]=backward_cell_state =========
__global__ __launch_bounds__(256) void prep_kernel(
    const float* __restrict__ attn_W, const float* __restrict__ attn_b, const float* __restrict__ attn_V,
    const float* __restrict__ l1_Wih, const float* __restrict__ l1_Whh,
    const float* __restrict__ l1_bih, const float* __restrict__ l1_bhh,
    const float* __restrict__ l2_Wih, const float* __restrict__ l2_Whh,
    const float* __restrict__ l2_bih, const float* __restrict__ l2_bhh,
    const float* __restrict__ bcs, char* __restrict__ ws)
{
  long gid = (long)blockIdx.x*256 + threadIdx.x;
  if (gid < 131072){
    int j = (int)(gid >> 8), k = (int)(gid & 255);
    float v = (j < 256) ? attn_W[j*512 + k] : attn_W[(j-256)*512 + 256 + k];
    ((f16*)(ws+O_WQV))[gid] = (f16)(K2E * v);
    return;
  }
  gid -= 131072;
  if (gid < 524288){ ((f16*)(ws+O_W1))[gid] = (f16)l1_Wih[gid]; return; }
  gid -= 524288;
  if (gid < 524288){ ((f16*)(ws+O_W2))[gid] = (f16)l2_Wih[gid]; return; }
  gid -= 524288;
  if (gid < 262144){ ((f16*)(ws+O_WHH1))[gid] = (f16)l1_Whh[gid]; return; }
  gid -= 262144;
  if (gid < 262144){ ((f16*)(ws+O_WHH2))[gid] = (f16)l2_Whh[gid]; return; }
  gid -= 262144;
  if (gid < 512){ ((float*)(ws+O_BQV))[gid] = (gid < 256) ? 0.f : K2E*attn_b[gid-256]; return; }
  gid -= 512;
  if (gid < 1024){ ((float*)(ws+O_B1))[gid] = l1_bih[gid] + l1_bhh[gid]; return; }
  gid -= 1024;
  if (gid < 1024){ ((float*)(ws+O_B2))[gid] = l2_bih[gid] + l2_bhh[gid]; return; }
  gid -= 1024;
  if (gid < 256){ ((float*)(ws+O_V2))[gid] = -2.f*attn_V[gid]; return; }
  gid -= 256;
  if (gid < 8192){
    int j = (int)(gid & 7), slot = (int)(gid >> 3);
    int m = slot & 31, kgrp = (slot >> 5) & 3, kc = slot >> 7;
    int k = kc*32 + kgrp*8 + j;
    ((f16*)(ws+O_CPUB))[8192 + gid] = (f16)bcs[m*256 + k];
    return;
  }
  gid -= 8192;
  if (gid == 0){
    float s = 0.f;
    for (int h=0; h<256; h++) s += attn_V[h];
    *((float*)(ws+O_SUMV)) = s;
  }
}

// ============ enc f32 -> f16 ============
__global__ __launch_bounds__(256) void encf_kernel(const float* __restrict__ enc, char* __restrict__ ws){
  f16* dst = (f16*)(ws + O_ENCF);
  int i = (blockIdx.x*256 + threadIdx.x)*4;
  float4 v = *(const float4*)(enc + i);
  f16x4 o; o[0] = (f16)v.x; o[1] = (f16)v.y; o[2] = (f16)v.z; o[3] = (f16)v.w;
  *(f16x4*)(dst + i) = o;
}

// ============ NT GEMM: C[M,N](f32|f16) = A[M,256(+256)] * B[N,K]^T + bias =========
template<bool CF16>
__global__ __launch_bounds__(256) void gemm_nt(const f16* __restrict__ A0, const f16* __restrict__ A1,
     int K0, const f16* __restrict__ B, int ldb, void* __restrict__ Cp, int ldc,
     int K, const float* __restrict__ bias)
{
  __shared__ f16 As[4096];
  __shared__ f16 Bs[4096];
  const int tid = threadIdx.x;
  const int lane = tid & 63;
  const int wave = tid >> 6;
  const int lm = lane & 15, kg = lane >> 4;
  const int mbase = blockIdx.y * 128;
  const int nbase = blockIdx.x * 128;
  const int wm = (wave >> 1) * 64, wn = (wave & 1) * 64;
  f32x4 acc[4][4];
#pragma unroll
  for (int i=0;i<4;i++)
#pragma unroll
    for (int j=0;j<4;j++) acc[i][j] = 0;
  const int r = tid >> 1, seg = tid & 1;
  for (int kc=0; kc<K; kc+=32){
    const f16* Ap = A0; int kk = kc;
    if (A1 && kc >= K0){ Ap = A1; kk = kc - K0; }
    {
      const f16* srcA = Ap + (size_t)(mbase + r)*256 + kk + seg*16;
      f16x8 va0 = *(const f16x8*)(srcA);
      f16x8 va1 = *(const f16x8*)(srcA + 8);
      *(f16x8*)&As[((seg*2+0)*128 + r)*8] = va0;
      *(f16x8*)&As[((seg*2+1)*128 + r)*8] = va1;
      const f16* srcB = B + (size_t)(nbase + r)*ldb + kc + seg*16;
      f16x8 vb0 = *(const f16x8*)(srcB);
      f16x8 vb1 = *(const f16x8*)(srcB + 8);
      *(f16x8*)&Bs[((seg*2+0)*128 + r)*8] = vb0;
      *(f16x8*)&Bs[((seg*2+1)*128 + r)*8] = vb1;
    }
    __syncthreads();
    f16x8 af[4], bfr[4];
#pragma unroll
    for (int i=0;i<4;i++) af[i]  = *(const f16x8*)&As[(kg*128 + wm + i*16 + lm)*8];
#pragma unroll
    for (int j=0;j<4;j++) bfr[j] = *(const f16x8*)&Bs[(kg*128 + wn + j*16 + lm)*8];
#pragma unroll
    for (int i=0;i<4;i++)
#pragma unroll
      for (int j=0;j<4;j++)
        acc[i][j] = __builtin_amdgcn_mfma_f32_16x16x32_f16(af[i], bfr[j], acc[i][j], 0,0,0);
    __syncthreads();
  }
#pragma unroll
  for (int i=0;i<4;i++){
#pragma unroll
    for (int j=0;j<4;j++){
      int col = nbase + wn + j*16 + lm;
      float bv = bias ? bias[col] : 0.f;
#pragma unroll
      for (int rr=0;rr<4;rr++){
        int row = mbase + wm + i*16 + kg*4 + rr;
        float v = acc[i][j][rr] + bv;
        if (CF16) ((f16*)Cp)[(size_t)row*ldc + col] = (f16)v;
        else      ((float*)Cp)[(size_t)row*ldc + col] = v;
      }
    }
  }
}

// ============ fused attention scores + softmax + ctx ============
__global__ __launch_bounds__(256) void score_ctx_kernel(char* __restrict__ ws,
     const float* __restrict__ enc, const int* __restrict__ inp_len)
{
  __shared__ float s_pq[8][260];
  __shared__ float s_pv[32][260];
  __shared__ float s_sc[8][512];
  __shared__ float s_v2[256];
  __shared__ float s_sv[1];
  const int tid = threadIdx.x;
  const int b = blockIdx.y;
  const int t0 = blockIdx.x * 8;
  const float* pqv = (const float*)(ws + O_PQV);
  f16* ctx = (f16*)(ws + O_CTX);
  const int len = inp_len[b];
  {
    int row = tid >> 5, cb = (tid & 31) * 8;
    const float* src = pqv + (size_t)(b*512 + t0 + row)*512 + cb;
    *(float4*)&s_pq[row][cb]   = *(const float4*)(src);
    *(float4*)&s_pq[row][cb+4] = *(const float4*)(src+4);
    s_v2[tid] = ((const float*)(ws + O_V2))[tid];
    if (tid == 0) s_sv[0] = *((const float*)(ws + O_SUMV));
  }
  const int tt = tid >> 5;
  const int ss2 = tid & 31;
  for (int st=0; st<16; st++){
    {
      int row = tid >> 3, cb = (tid & 7) * 32;
      const float* src = pqv + (size_t)(b*512 + st*32 + row)*512 + 256 + cb;
#pragma unroll
      for (int c=0;c<32;c+=4) *(float4*)&s_pv[row][cb+c] = *(const float4*)(src+c);
    }
    __syncthreads();
    float a0=0.f,a1=0.f,a2=0.f,a3=0.f;
#pragma unroll 8
    for (int h=0;h<256;h+=4){
      float4 q = *(const float4*)&s_pq[tt][h];
      float4 p = *(const float4*)&s_pv[ss2][h];
      float4 w = *(const float4*)&s_v2[h];
      float e0 = __builtin_amdgcn_exp2f(q.x+p.x);
      float e1 = __builtin_amdgcn_exp2f(q.y+p.y);
      float e2 = __builtin_amdgcn_exp2f(q.z+p.z);
      float e3 = __builtin_amdgcn_exp2f(q.w+p.w);
      a0 += w.x * __builtin_amdgcn_rcpf(1.f+e0);
      a1 += w.y * __builtin_amdgcn_rcpf(1.f+e1);
      a2 += w.z * __builtin_amdgcn_rcpf(1.f+e2);
      a3 += w.w * __builtin_amdgcn_rcpf(1.f+e3);
    }
    int s = st*32 + ss2;
    float sc = s_sv[0] + ((a0+a1)+(a2+a3));
    if (s >= len) sc = -1.0e9f;
    s_sc[tt][s] = sc;
    __syncthreads();
  }
  {
    float m = -3.0e38f;
#pragma unroll
    for (int k2=0;k2<16;k2++) m = fmaxf(m, s_sc[tt][ss2 + 32*k2]);
#pragma unroll
    for (int off=16; off>=1; off>>=1) m = fmaxf(m, __shfl_xor(m, off, 64));
    float sum = 0.f;
    float ebuf[16];
#pragma unroll
    for (int k2=0;k2<16;k2++){
      float e = __builtin_amdgcn_exp2f((s_sc[tt][ss2+32*k2] - m) * L2E);
      ebuf[k2] = e; sum += e;
    }
#pragma unroll
    for (int off=16; off>=1; off>>=1) sum += __shfl_xor(sum, off, 64);
    float rinv = __builtin_amdgcn_rcpf(sum);
#pragma unroll
    for (int k2=0;k2<16;k2++) s_sc[tt][ss2+32*k2] = ebuf[k2]*rinv;
  }
  __syncthreads();
  float acc[8] = {0,0,0,0,0,0,0,0};
  const int hg = tid & 31;
  for (int st=0; st<16; st++){
    {
      int row = tid >> 3, cb = (tid & 7)*32;
      const float* src = enc + (size_t)(b*512 + st*32 + row)*256 + cb;
#pragma unroll
      for (int c=0;c<32;c+=4) *(float4*)&s_pv[row][cb+c] = *(const float4*)(src+c);
    }
    __syncthreads();
#pragma unroll 4
    for (int si=0; si<32; si++){
      float a = s_sc[tt][st*32+si];
#pragma unroll
      for (int u=0;u<8;u++) acc[u] += a * s_pv[si][hg + 32*u];
    }
    __syncthreads();
  }
#pragma unroll
  for (int u=0;u<8;u++)
    ctx[(size_t)(b*512 + t0 + tt)*256 + hg + 32*u] = (f16)acc[u];
}

// ============ recurrences: 16 blocks layer-1 + 16 blocks layer-2 ============
// per-wave flags on private 128B lines; no publish barrier; no sleep in polls.
__global__ __launch_bounds__(256) void rec_kernel(char* __restrict__ ws,
        const float* __restrict__ bhs, const int* __restrict__ inp_len,
        float* __restrict__ out)
{
  __shared__ float s_g[4][32][17];
  const int tid = threadIdx.x;
  const int lane = tid & 63;
  const int wave = tid >> 6;
  const int lm = lane & 15;
  const int kg = lane >> 4;
  int* pflag1 = (int*)(ws + O_FLAGS);
  int* pflag2 = pflag1 + 64*32;
  f16* cpub  = (f16*)(ws + O_CPUB);
  f16* h2pub = (f16*)(ws + O_H2PUB);
  f16* decp  = (f16*)(ws + O_DECH);
  // gate-phase mapping: one batch, two adjacent k-components per thread
  const int b  = tid >> 3;
  const int kp = tid & 7;
  const int kl0 = kp*2, kl1 = kp*2 + 1;

  if (blockIdx.x < 16) {
    // ---- layer 1 (reference quirk: matmul uses carry c; c_new = f*h_prev + i*g~)
    const int isl = blockIdx.x;
    const int slot = isl*4 + wave;
    const f16* whh1 = (const f16*)(ws + O_WHH1);
    const f16* gih1 = (const f16*)(ws + O_GIH1);
    f16x8 bf[8];
    {
      int j = wave*256 + isl*16 + lm;
#pragma unroll
      for (int kc=0;kc<8;kc++) bf[kc] = *(const f16x8*)(whh1 + j*256 + kc*32 + kg*8);
    }
    float h0 = bhs[b*256 + isl*16 + kl0];
    float h1 = bhs[b*256 + isl*16 + kl1];
    const int kk0 = isl*16 + kl0;
    const int ppos = (((kk0>>5)<<7) + (((kk0>>3)&3)<<5))*8 + (kk0&7) + (b<<3);
    for (int t=0;t<512;t++){
      // prefetch gih (plain cached loads, address depends only on t)
      const f16* gp = gih1 + (size_t)(b*512 + t)*1024 + isl*16 + kl0;
      f16x2 gv0 = *(const f16x2*)(gp);
      f16x2 gv1 = *(const f16x2*)(gp+256);
      f16x2 gv2 = *(const f16x2*)(gp+512);
      f16x2 gv3 = *(const f16x2*)(gp+768);
      wait_flags_pw<false>(pflag1, t, nullptr, 0, tid);
      const f16* cp = cpub + (((t+1)&1)<<13);
      f32x4 acc0 = 0, acc1 = 0;
#pragma unroll
      for (int kc=0;kc<8;kc++){
        f16x8 a0 = load_a8_coh(cp + ((kc<<7) + (kg<<5) + lm)*8);
        f16x8 a1 = load_a8_coh(cp + ((kc<<7) + (kg<<5) + 16 + lm)*8);
        acc0 = __builtin_amdgcn_mfma_f32_16x16x32_f16(a0, bf[kc], acc0, 0,0,0);
        acc1 = __builtin_amdgcn_mfma_f32_16x16x32_f16(a1, bf[kc], acc1, 0,0,0);
      }
#pragma unroll
      for (int rr=0;rr<4;rr++){
        s_g[wave][kg*4+rr][lm] = acc0[rr];
        s_g[wave][16+kg*4+rr][lm] = acc1[rr];
      }
      __syncthreads();
      {
        float gi0 = s_g[0][b][kl0] + (float)gv0[0];
        float gi1 = s_g[0][b][kl1] + (float)gv0[1];
        float gf0 = s_g[1][b][kl0] + (float)gv1[0];
        float gf1 = s_g[1][b][kl1] + (float)gv1[1];
        float gc0 = s_g[2][b][kl0] + (float)gv2[0];
        float gc1 = s_g[2][b][kl1] + (float)gv2[1];
        float go0 = s_g[3][b][kl0] + (float)gv3[0];
        float go1 = s_g[3][b][kl1] + (float)gv3[1];
        float cn0 = fast_sigmoid(gf0)*h0 + fast_sigmoid(gi0)*fast_tanh(gc0);  // quirk
        float cn1 = fast_sigmoid(gf1)*h1 + fast_sigmoid(gi1)*fast_tanh(gc1);
        float hn0 = fast_sigmoid(go0)*fast_tanh(cn0);
        float hn1 = fast_sigmoid(go1)*fast_tanh(cn1);
        h0 = hn0; h1 = hn1;
        store_pair_wt(cpub + ((t&1)<<13) + ppos, cn0, cn1);
        store_pair_wt(decp + (t<<13) + ppos, hn0, hn1);
      }
      publish_wave(pflag1, slot, t+1, lane);
    }
  } else {
    // ---- layer 2 (standard cell, masked freeze)
    const int isl = blockIdx.x - 16;
    const int slot = isl*4 + wave;
    const f16* whh2 = (const f16*)(ws + O_WHH2);
    const f16* w2   = (const f16*)(ws + O_W2);
    const f16* gih2 = (const f16*)(ws + O_GIH2C);
    f16x8 bfh[8], bfx[8];
    {
      int j = wave*256 + isl*16 + lm;
#pragma unroll
      for (int kc=0;kc<8;kc++){
        bfh[kc] = *(const f16x8*)(whh2 + j*256 + kc*32 + kg*8);
        bfx[kc] = *(const f16x8*)(w2 + j*512 + kc*32 + kg*8);
      }
    }
    float c0 = 0.f, c1 = 0.f, hh0 = 0.f, hh1 = 0.f;
    const int lenv = inp_len[b];
    const int kk0 = isl*16 + kl0;
    const int ppos = (((kk0>>5)<<7) + (((kk0>>3)&3)<<5))*8 + (kk0&7) + (b<<3);
    for (int t=0;t<512;t++){
      const f16* gp = gih2 + (size_t)(b*512 + t)*1024 + isl*16 + kl0;
      f16x2 gv0 = *(const f16x2*)(gp);
      f16x2 gv1 = *(const f16x2*)(gp+256);
      f16x2 gv2 = *(const f16x2*)(gp+512);
      f16x2 gv3 = *(const f16x2*)(gp+768);
      wait_flags_pw<true>(pflag1, t+1, pflag2, t, tid);
      const f16* xp = decp + (t<<13);
      const f16* hp = h2pub + (((t+1)&1)<<13);
      f32x4 acc0 = 0, acc1 = 0;
#pragma unroll
      for (int kc=0;kc<8;kc++){
        int off = ((kc<<7) + (kg<<5) + lm)*8;
        f16x8 ax0 = load_a8_coh(xp + off);
        f16x8 ax1 = load_a8_coh(xp + off + 128);
        f16x8 ah0 = load_a8_coh(hp + off);
        f16x8 ah1 = load_a8_coh(hp + off + 128);
        acc0 = __builtin_amdgcn_mfma_f32_16x16x32_f16(ax0, bfx[kc], acc0, 0,0,0);
        acc1 = __builtin_amdgcn_mfma_f32_16x16x32_f16(ax1, bfx[kc], acc1, 0,0,0);
        acc0 = __builtin_amdgcn_mfma_f32_16x16x32_f16(ah0, bfh[kc], acc0, 0,0,0);
        acc1 = __builtin_amdgcn_mfma_f32_16x16x32_f16(ah1, bfh[kc], acc1, 0,0,0);
      }
#pragma unroll
      for (int rr=0;rr<4;rr++){
        s_g[wave][kg*4+rr][lm] = acc0[rr];
        s_g[wave][16+kg*4+rr][lm] = acc1[rr];
      }
      __syncthreads();
      float ov0, ov1;
      {
        float gi0 = s_g[0][b][kl0] + (float)gv0[0];
        float gi1 = s_g[0][b][kl1] + (float)gv0[1];
        float gf0 = s_g[1][b][kl0] + (float)gv1[0];
        float gf1 = s_g[1][b][kl1] + (float)gv1[1];
        float gc0 = s_g[2][b][kl0] + (float)gv2[0];
        float gc1 = s_g[2][b][kl1] + (float)gv2[1];
        float go0 = s_g[3][b][kl0] + (float)gv3[0];
        float go1 = s_g[3][b][kl1] + (float)gv3[1];
        float cn0 = fast_sigmoid(gf0)*c0 + fast_sigmoid(gi0)*fast_tanh(gc0);
        float cn1 = fast_sigmoid(gf1)*c1 + fast_sigmoid(gi1)*fast_tanh(gc1);
        float hn0 = fast_sigmoid(go0)*fast_tanh(cn0);
        float hn1 = fast_sigmoid(go1)*fast_tanh(cn1);
        bool valid = (t < lenv);
        c0 = valid ? cn0 : c0;
        c1 = valid ? cn1 : c1;
        hh0 = valid ? hn0 : hh0;
        hh1 = valid ? hn1 : hh1;
        ov0 = valid ? hn0 : 0.f;
        ov1 = valid ? hn1 : 0.f;
        store_pair_wt(h2pub + ((t&1)<<13) + ppos, hh0, hh1);
      }
      publish_wave(pflag2, slot, t+1, lane);
      // out store AFTER flag publish: HBM-latency store off the critical sync path
      float2 ov; ov.x = ov0; ov.y = ov1;
      *(float2*)(out + (size_t)(b*512 + t)*256 + isl*16 + kl0) = ov;
    }
  }
}

extern "C" void kernel_launch(void* const* d_in, const int* in_sizes, int n_in,
                              void* d_out, int out_size, void* d_ws, size_t ws_size,
                              hipStream_t stream) {
  if (ws_size < WS_NEED) return;  // workspace too small; bail (output stays poison -> visible failure)
  const float* enc    = (const float*)d_in[0];
  const float* bhs    = (const float*)d_in[1];
  const float* bcs    = (const float*)d_in[2];
  const float* attn_W = (const float*)d_in[3];
  const float* attn_b = (const float*)d_in[4];
  const float* attn_V = (const float*)d_in[5];
  const float* l1_Wih = (const float*)d_in[6];
  const float* l1_Whh = (const float*)d_in[7];
  const float* l1_bih = (const float*)d_in[8];
  const float* l1_bhh = (const float*)d_in[9];
  const float* l2_Wih = (const float*)d_in[10];
  const float* l2_Whh = (const float*)d_in[11];
  const float* l2_bih = (const float*)d_in[12];
  const float* l2_bhh = (const float*)d_in[13];
  const int* inp_len  = (const int*)d_in[14];
  char* ws = (char*)d_ws;
  float* out = (float*)d_out;

  hipMemsetAsync(ws + O_CPUB, 0, (size_t)(WS_NEED - O_CPUB), stream);
  prep_kernel<<<6700, 256, 0, stream>>>(attn_W, attn_b, attn_V, l1_Wih, l1_Whh, l1_bih, l1_bhh,
                                        l2_Wih, l2_Whh, l2_bih, l2_bhh, bcs, ws);
  encf_kernel<<<4096, 256, 0, stream>>>(enc, ws);
  // pqv = k2*(enc@Wq^T | enc@Wv^T + b)
  gemm_nt<false><<<dim3(4,128), 256, 0, stream>>>((const f16*)(ws+O_ENCF), nullptr, 256,
        (const f16*)(ws+O_WQV), 256, (void*)(ws+O_PQV), 512, 256, (const float*)(ws+O_BQV));
  score_ctx_kernel<<<dim3(64,32), 256, 0, stream>>>(ws, enc, inp_len);
  // gih1 = [enc|ctx]@W1^T + (bih1+bhh1)
  gemm_nt<true><<<dim3(8,128), 256, 0, stream>>>((const f16*)(ws+O_ENCF), (const f16*)(ws+O_CTX), 256,
        (const f16*)(ws+O_W1), 512, (void*)(ws+O_GIH1), 1024, 512, (const float*)(ws+O_B1));
  // gih2c = ctx@W2R^T + (bih2+bhh2)   (aliases pqv region; pqv dead after score_ctx)
  gemm_nt<true><<<dim3(8,128), 256, 0, stream>>>((const f16*)(ws+O_CTX), nullptr, 256,
        (const f16*)(ws+O_W2)+256, 512, (void*)(ws+O_GIH2C), 1024, 256, (const float*)(ws+O_B2));
  rec_kernel<<<32, 256, 0, stream>>>(ws, bhs, inp_len, out);
}